// Round 2
// baseline (1176.715 us; speedup 1.0000x reference)
//
#include <hip/hip_runtime.h>
#include <hip/hip_bf16.h>

#define D 64
#define BK_A 8192        // edges per bucketing block
#define RNG_SHIFT 7
#define RNG 128          // nodes per bucket (pow2 so bkt = dst >> 7)

// ---------------- K1: fused edge-bucketing + pre-GEMM ----------------
// Heterogeneous blocks, Bresenham-interleaved so bucketing blocks start early
// and overlap the compute-bound pre-GEMM tiles (time ~ max, not sum).
//
// Bucketing path: per edge, append packed (dst_local<<17 | src) into the
// bucket region of dst's 128-node range. Appends are position-dense per
// bucket -> full 64B lines -> L2 merges -> edge write traffic ~= compact
// 6.4MB instead of the per-node-slots ~100MB (R0 counters: WRITE_SIZE 127MB
// vs 45MB ideal was the dominant loss).
// NOTE: packing assumes nN <= 2^17 (=131072); holds here (100000).
//
// Pre path: unchanged proven code: ylb = x@W_l (bf16), out = x@W_r + b (f32).
__global__ __launch_bounds__(256) void k_fused(
        const float* __restrict__ x, const int* __restrict__ src,
        const int* __restrict__ dst, const float* __restrict__ Wl,
        const float* __restrict__ Wr, const float* __restrict__ b,
        int* __restrict__ bcnt, unsigned int* __restrict__ pairs,
        unsigned short* __restrict__ ylb, float* __restrict__ out,
        int nE, int nN, int capB, int nA, int total) {
    __shared__ float sX[64 * 65];   // stride 65: <=2-way bank alias (free)
    __shared__ float sB[64];

    const int bid = blockIdx.x;
    const int t = threadIdx.x;

    // Bresenham interleave: nA bucketing blocks spread evenly among total.
    const long long lo = ((long long)bid * nA) / total;
    const long long hi = ((long long)(bid + 1) * nA) / total;

    if (hi > lo) {
        // ---- bucketing path: chunk lo of BK_A edges ----
        const int e0 = (int)lo * BK_A;
        const int e1 = min(e0 + BK_A, nE);
        for (int e = e0 + t; e < e1; e += 256) {
            int dn = dst[e];
            int sn = src[e];
            int bk = dn >> RNG_SHIFT;
            int pos = atomicAdd(&bcnt[bk], 1);   // 782 counters, ~2046 each
            if (pos < capB)
                pairs[(size_t)bk * capB + pos] =
                    ((unsigned)(dn & (RNG - 1)) << 17) | (unsigned)sn;
        }
        return;
    }

    // ---- pre path: tile g (64 nodes) ----
    const int g = bid - (int)lo;
    const int lane = t & 63, wv = t >> 6;
    const int tile = g * 64;
    if (t < 64) sB[t] = b[t];
    for (int q = 0; q < 16; ++q) {
        int nd = wv * 16 + q, gg = tile + nd;
        sX[nd * 65 + lane] = (gg < nN) ? x[(size_t)gg * D + lane] : 0.f;
    }
    __syncthreads();

    const int n0 = (t & 15) * 4;
    const int c0 = (t >> 4) * 4;
    float accl[4][4] = {}, accr[4][4] = {};
#pragma unroll 4
    for (int k = 0; k < D; ++k) {
        float a0 = sX[(n0 + 0) * 65 + k], a1 = sX[(n0 + 1) * 65 + k];
        float a2 = sX[(n0 + 2) * 65 + k], a3 = sX[(n0 + 3) * 65 + k];
        float4 wl4 = *(const float4*)&Wl[k * D + c0];   // 16-lane broadcast, L1-resident
        float4 wr4 = *(const float4*)&Wr[k * D + c0];
        accl[0][0] += a0 * wl4.x; accl[0][1] += a0 * wl4.y; accl[0][2] += a0 * wl4.z; accl[0][3] += a0 * wl4.w;
        accl[1][0] += a1 * wl4.x; accl[1][1] += a1 * wl4.y; accl[1][2] += a1 * wl4.z; accl[1][3] += a1 * wl4.w;
        accl[2][0] += a2 * wl4.x; accl[2][1] += a2 * wl4.y; accl[2][2] += a2 * wl4.z; accl[2][3] += a2 * wl4.w;
        accl[3][0] += a3 * wl4.x; accl[3][1] += a3 * wl4.y; accl[3][2] += a3 * wl4.z; accl[3][3] += a3 * wl4.w;
        accr[0][0] += a0 * wr4.x; accr[0][1] += a0 * wr4.y; accr[0][2] += a0 * wr4.z; accr[0][3] += a0 * wr4.w;
        accr[1][0] += a1 * wr4.x; accr[1][1] += a1 * wr4.y; accr[1][2] += a1 * wr4.z; accr[1][3] += a1 * wr4.w;
        accr[2][0] += a2 * wr4.x; accr[2][1] += a2 * wr4.y; accr[2][2] += a2 * wr4.z; accr[2][3] += a2 * wr4.w;
        accr[3][0] += a3 * wr4.x; accr[3][1] += a3 * wr4.y; accr[3][2] += a3 * wr4.z; accr[3][3] += a3 * wr4.w;
    }

#pragma unroll
    for (int i = 0; i < 4; ++i) {
        int gg = tile + n0 + i;
        if (gg >= nN) continue;
        __hip_bfloat162 l01 = __float22bfloat162_rn(make_float2(accl[i][0], accl[i][1]));
        __hip_bfloat162 l23 = __float22bfloat162_rn(make_float2(accl[i][2], accl[i][3]));
        uint2 pl = make_uint2(*(unsigned int*)&l01, *(unsigned int*)&l23);
        *(uint2*)&ylb[(size_t)gg * D + c0] = pl;
        float4 o;
        o.x = accr[i][0] + sB[c0 + 0];
        o.y = accr[i][1] + sB[c0 + 1];
        o.z = accr[i][2] + sB[c0 + 2];
        o.w = accr[i][3] + sB[c0 + 3];
        *(float4*)&out[(size_t)gg * D + c0] = o;   // self term, f32, no relu yet
    }
}

// ---------------- K2: per-bucket LDS aggregation + finalize ----------------
// One block per 128-node bucket. 128x64 f32 accumulator in LDS (32KB).
// Per edge: one 128B ylb row read (LLC-resident, 12.8MB total) + one
// wave-wide ds_add into sAgg[dl*64+lane] -> bank = lane&31 -> exactly 2-way
// (free per m136). Degree from LDS histogram of the same entries (exact).
__global__ __launch_bounds__(256) void k_agg(
        const unsigned short* __restrict__ ylb, const int* __restrict__ bcnt,
        const unsigned int* __restrict__ pairs, float* __restrict__ out,
        int nN, int capB) {
    __shared__ float sAgg[RNG * D];   // 32KB
    __shared__ int sCnt[RNG];

    const int bkt = blockIdx.x;
    const int t = threadIdx.x;
    const int lane = t & 63, wv = t >> 6;   // 4 waves

    for (int i = t; i < RNG * D; i += 256) sAgg[i] = 0.f;
    if (t < RNG) sCnt[t] = 0;
    __syncthreads();

    const int n = min(bcnt[bkt], capB);
    const int per = (n + 3) >> 2;           // contiguous quarter per wave
    const int s0 = min(wv * per, n);
    const int s1 = min(s0 + per, n);
    const size_t pb = (size_t)bkt * capB;

    for (int kk = s0; kk < s1; kk += 64) {
        const int m = min(64, s1 - kk);
        unsigned ent = (lane < m) ? pairs[pb + kk + lane] : 0u;
        // degree histogram: one wave-wide LDS atomic per 64 edges
        if (lane < m) atomicAdd(&sCnt[ent >> 17], 1);

        int k = 0;
        for (; k + 4 <= m; k += 4) {
            unsigned e0 = __shfl(ent, k, 64),     e1 = __shfl(ent, k + 1, 64);
            unsigned e2 = __shfl(ent, k + 2, 64), e3 = __shfl(ent, k + 3, 64);
            // 4 independent 128B row loads in flight (latency hiding)
            unsigned short u0 = ylb[(size_t)(e0 & 0x1FFFFu) * D + lane];
            unsigned short u1 = ylb[(size_t)(e1 & 0x1FFFFu) * D + lane];
            unsigned short u2 = ylb[(size_t)(e2 & 0x1FFFFu) * D + lane];
            unsigned short u3 = ylb[(size_t)(e3 & 0x1FFFFu) * D + lane];
            atomicAdd(&sAgg[(e0 >> 17) * D + lane], __uint_as_float((unsigned)u0 << 16));
            atomicAdd(&sAgg[(e1 >> 17) * D + lane], __uint_as_float((unsigned)u1 << 16));
            atomicAdd(&sAgg[(e2 >> 17) * D + lane], __uint_as_float((unsigned)u2 << 16));
            atomicAdd(&sAgg[(e3 >> 17) * D + lane], __uint_as_float((unsigned)u3 << 16));
        }
        for (; k < m; ++k) {
            unsigned e0 = __shfl(ent, k, 64);
            unsigned short u0 = ylb[(size_t)(e0 & 0x1FFFFu) * D + lane];
            atomicAdd(&sAgg[(e0 >> 17) * D + lane], __uint_as_float((unsigned)u0 << 16));
        }
    }
    __syncthreads();

    // finalize: mean + self term + relu; coalesced
    const int gBase = bkt * RNG;
    for (int i = t; i < RNG * D; i += 256) {
        int nd = i >> 6;
        int gg = gBase + nd;
        if (gg >= nN) break;   // i monotone increasing -> safe
        float inv = 1.f / fmaxf((float)sCnt[nd], 1.f);
        size_t o = (size_t)gg * D + (i & 63);
        out[o] = fmaxf(sAgg[i] * inv + out[o], 0.f);
    }
}

extern "C" void kernel_launch(void* const* d_in, const int* in_sizes, int n_in,
                              void* d_out, int out_size, void* d_ws, size_t ws_size,
                              hipStream_t stream) {
    const float* x  = (const float*)d_in[0];
    const int*   ei = (const int*)d_in[1];      // [2, E]: row 0 = src, row 1 = dst
    const float* Wl = (const float*)d_in[2];
    const float* Wr = (const float*)d_in[3];
    const float* b  = (const float*)d_in[4];
    float*       out = (float*)d_out;

    const int nN = in_sizes[0] / D;   // 100000
    const int nE = in_sizes[1] / 2;   // 1600000
    const int* src = ei;
    const int* dst = ei + nE;

    const int nB = (nN + RNG - 1) >> RNG_SHIFT;   // 782 buckets

    // ws layout: bcnt[nB] | pairs[nB*capB] | ylb[nN*64 bf16]
    // DEFENSIVE sizing (R1 lesson: size_t underflow here could send pairs
    // past the workspace and hard-crash). Signed math, clamped.
    long long ws_words  = (long long)(ws_size / 4);
    long long ylb_words = (long long)nN * (D / 2);
    long long spare = ws_words - ylb_words - (long long)nB - 8;
    if (spare < 0) spare = 0;
    long long capS = spare / (long long)nB;
    // mean bucket load = nE*RNG/nN ~= 2048, sd ~= 45. 4096 is >40 sd;
    // anything >= 2560 is >11 sd. Clamp into [0, 4096].
    int capB = capS > 4096 ? 4096 : (int)capS;

    int* bcnt = (int*)d_ws;
    unsigned int* pairs = (unsigned int*)(bcnt + nB);
    size_t off = (size_t)nB + (size_t)nB * (size_t)capB;
    off = (off + 3) & ~(size_t)3;                 // 16B-align ylb
    unsigned short* ylb = (unsigned short*)((int*)d_ws + off);

    hipMemsetAsync(bcnt, 0, (size_t)nB * sizeof(int), stream);

    const int nA   = (nE + BK_A - 1) / BK_A;      // 196 bucketing blocks
    const int nPre = (nN + 63) / 64;              // 1563 pre-GEMM tiles
    const int total = nA + nPre;                  // 1759, interleaved

    k_fused<<<total, 256, 0, stream>>>(x, src, dst, Wl, Wr, b,
                                       bcnt, pairs, ylb, out, nE, nN, capB, nA, total);
    k_agg<<<nB, 256, 0, stream>>>(ylb, bcnt, pairs, out, nN, capB);
}

// Round 3
// 200.843 us; speedup vs baseline: 5.8589x; 5.8589x over previous
//
#include <hip/hip_runtime.h>
#include <hip/hip_bf16.h>

#define D 64
#define CHUNK 8192        // edges per scatter chunk-block
#define NBKT_SHIFT 7      // 128 nodes per bucket
#define PAD 16            // cursor padding: one counter per 64B line (R2 lesson)

// ---------------- K1 combo: pre-GEMM  ||  chunked edge scatter ----------------
// Scatter role (196 blocks, Bresenham-interleaved): per 8192-edge chunk:
//   (a) LDS int histogram over 782 buckets (native ds_add, fast)
//   (b) ONE global atomicAdd per nonzero (chunk,bucket): ~153K total atomics
//       (vs 1.6M in R0 -> the measured ~25-33cy/op-per-line atomic wall drops
//       from ~130us to ~15us). Cursors padded one-per-line.
//   (c) re-stream edges, LDS rank, write packed (dloc<<17|src) into the
//       bucket's reserved run in pairs[].
// Pre role (1563 blocks): verbatim proven path: ylb = x@W_l (bf16),
// out = x@W_r + b (f32, no relu yet).
__global__ __launch_bounds__(256) void k_combo(
        const float* __restrict__ x, const int* __restrict__ src,
        const int* __restrict__ dst, const float* __restrict__ Wl,
        const float* __restrict__ Wr, const float* __restrict__ b,
        int* __restrict__ cursor, int* __restrict__ pairs,
        unsigned short* __restrict__ ylb, float* __restrict__ out,
        int nE, int nN, int nB, int capB, int nA, int total) {
    __shared__ float sX[64 * 65];   // 16.6KB, stride 65: 2-way alias (free)
    __shared__ float sB[64];
    __shared__ int hA[800], bL[800], hC[800];   // 9.6KB, 782 used

    const int bid = blockIdx.x;
    const int t = threadIdx.x;

    const long long lo = ((long long)bid * nA) / total;
    const long long hi = ((long long)(bid + 1) * nA) / total;

    if (hi > lo) {
        // ---- scatter role: chunk lo ----
        const int e0 = (int)lo * CHUNK;
        const int e1 = min(e0 + CHUNK, nE);
        for (int i = t; i < nB; i += 256) { hA[i] = 0; hC[i] = 0; }
        __syncthreads();
        // (a) histogram (native LDS int atomics)
        for (int e = e0 + t; e < e1; e += 256)
            atomicAdd(&hA[dst[e] >> NBKT_SHIFT], 1);
        __syncthreads();
        // (b) reserve one run per nonzero bucket (~782 global atomics/chunk)
        for (int i = t; i < nB; i += 256) {
            int c = hA[i];
            bL[i] = (c > 0) ? atomicAdd(&cursor[i * PAD], c) : 0;
        }
        __syncthreads();
        // (c) rank + write (ranks are any permutation within the run: OK)
        for (int e = e0 + t; e < e1; e += 256) {
            int dn = dst[e], sn = src[e];
            int bk = dn >> NBKT_SHIFT;
            int r = atomicAdd(&hC[bk], 1);
            int p = bL[bk] + r;
            if (p < capB)   // >40-sigma guard
                pairs[(size_t)bk * capB + p] = ((dn & 127) << 17) | sn;
        }
        return;
    }

    // ---- pre role: tile g (64 nodes), verbatim proven ----
    const int g = bid - (int)lo;
    const int lane = t & 63, wv = t >> 6;
    const int tile = g * 64;
    if (t < 64) sB[t] = b[t];
    for (int q = 0; q < 16; ++q) {
        int nd = wv * 16 + q, gg = tile + nd;
        sX[nd * 65 + lane] = (gg < nN) ? x[(size_t)gg * D + lane] : 0.f;
    }
    __syncthreads();

    const int n0 = (t & 15) * 4;
    const int c0 = (t >> 4) * 4;
    float accl[4][4] = {}, accr[4][4] = {};
#pragma unroll 4
    for (int k = 0; k < D; ++k) {
        float a0 = sX[(n0 + 0) * 65 + k], a1 = sX[(n0 + 1) * 65 + k];
        float a2 = sX[(n0 + 2) * 65 + k], a3 = sX[(n0 + 3) * 65 + k];
        float4 wl4 = *(const float4*)&Wl[k * D + c0];
        float4 wr4 = *(const float4*)&Wr[k * D + c0];
        accl[0][0] += a0 * wl4.x; accl[0][1] += a0 * wl4.y; accl[0][2] += a0 * wl4.z; accl[0][3] += a0 * wl4.w;
        accl[1][0] += a1 * wl4.x; accl[1][1] += a1 * wl4.y; accl[1][2] += a1 * wl4.z; accl[1][3] += a1 * wl4.w;
        accl[2][0] += a2 * wl4.x; accl[2][1] += a2 * wl4.y; accl[2][2] += a2 * wl4.z; accl[2][3] += a2 * wl4.w;
        accl[3][0] += a3 * wl4.x; accl[3][1] += a3 * wl4.y; accl[3][2] += a3 * wl4.z; accl[3][3] += a3 * wl4.w;
        accr[0][0] += a0 * wr4.x; accr[0][1] += a0 * wr4.y; accr[0][2] += a0 * wr4.z; accr[0][3] += a0 * wr4.w;
        accr[1][0] += a1 * wr4.x; accr[1][1] += a1 * wr4.y; accr[1][2] += a1 * wr4.z; accr[1][3] += a1 * wr4.w;
        accr[2][0] += a2 * wr4.x; accr[2][1] += a2 * wr4.y; accr[2][2] += a2 * wr4.z; accr[2][3] += a2 * wr4.w;
        accr[3][0] += a3 * wr4.x; accr[3][1] += a3 * wr4.y; accr[3][2] += a3 * wr4.z; accr[3][3] += a3 * wr4.w;
    }

#pragma unroll
    for (int i = 0; i < 4; ++i) {
        int gg = tile + n0 + i;
        if (gg >= nN) continue;
        __hip_bfloat162 l01 = __float22bfloat162_rn(make_float2(accl[i][0], accl[i][1]));
        __hip_bfloat162 l23 = __float22bfloat162_rn(make_float2(accl[i][2], accl[i][3]));
        uint2 pl = make_uint2(*(unsigned int*)&l01, *(unsigned int*)&l23);
        *(uint2*)&ylb[(size_t)gg * D + c0] = pl;
        float4 o;
        o.x = accr[i][0] + sB[c0 + 0];
        o.y = accr[i][1] + sB[c0 + 1];
        o.z = accr[i][2] + sB[c0 + 2];
        o.w = accr[i][3] + sB[c0 + 3];
        *(float4*)&out[(size_t)gg * D + c0] = o;
    }
}

// ---------------- K2: bucket-grouped -> per-node slot layout (in-place) ------
// One block per bucket. Stage the bucket's <=5760 entries in REGISTERS with
// static indexing (rule #20: no runtime-indexed local arrays), barrier (all
// loads drained before any store -> in-place safe), then rank via native LDS
// int atomics and scatter to slots position nd*capN + rank. Writes exact
// per-node degree to cnt. Zero global atomics.
__global__ __launch_bounds__(256) void k_sort(
        int* __restrict__ pairs, const int* __restrict__ cursor,
        int* __restrict__ cnt, int nN, int nB, int capB, int capN) {
    __shared__ int h[128];
    const int bkt = blockIdx.x;
    const int t = threadIdx.x;
    const size_t base = (size_t)bkt * capB;

    if (t < 128) h[t] = 0;
    const int n = min(cursor[bkt * PAD], capB);

    int st[23];   // 23*256 = 5888 >= capB max 5760
#pragma unroll
    for (int j = 0; j < 23; ++j) {
        int i = t + j * 256;
        st[j] = (i < n) ? pairs[base + i] : -1;
    }
    __syncthreads();   // loads drained (implicit vmcnt(0)) + h zeroed

#pragma unroll
    for (int j = 0; j < 23; ++j) {
        int v = st[j];
        if (v >= 0 && v < (1 << 24)) {   // valid payload only
            int dl = v >> 17;
            int r = atomicAdd(&h[dl], 1);
            if (r < capN) pairs[base + dl * capN + r] = v & 0x1FFFF;
        }
    }
    __syncthreads();

    if (t < 128) {
        int nd = bkt * 128 + t;
        if (nd < nN) cnt[nd] = h[t];   // exact degree
    }
}

// ---------------- K3: gather-mean + finalize (R0-proven, verbatim) -----------
// slots is node-linear: bucket*capB + dloc*capN == node*capN.
__device__ __forceinline__ float bl(unsigned p) { return __uint_as_float(p << 16); }
__device__ __forceinline__ float bh(unsigned p) { return __uint_as_float(p & 0xffff0000u); }

__global__ __launch_bounds__(256) void k_gather(
        const unsigned int* __restrict__ ylb, const int* __restrict__ cnt,
        const int* __restrict__ slots, float* __restrict__ out, int nN, int cap) {
    const int t = threadIdx.x;
    const int lane32 = t & 31;
    const int node = blockIdx.x * 8 + (t >> 5);
    if (node >= nN) return;

    const int deg = cnt[node];
    const int n = min(deg, cap);
    const size_t base = (size_t)node * cap;

    int idxA = (lane32 < n) ? slots[base + lane32] : 0;
    int idxB = (32 + lane32 < n) ? slots[base + 32 + lane32] : 0;

    float s0 = 0.f, s1 = 0.f, t0 = 0.f, t1 = 0.f;
    float u0 = 0.f, u1 = 0.f, v0 = 0.f, v1 = 0.f;

    const int n1 = min(n, 32);
    int k = 0;
    for (; k + 4 <= n1; k += 4) {
        int i0 = __shfl(idxA, k, 32), i1 = __shfl(idxA, k + 1, 32);
        int i2 = __shfl(idxA, k + 2, 32), i3 = __shfl(idxA, k + 3, 32);
        unsigned p0 = ylb[(size_t)i0 * 32 + lane32];
        unsigned p1 = ylb[(size_t)i1 * 32 + lane32];
        unsigned p2 = ylb[(size_t)i2 * 32 + lane32];
        unsigned p3 = ylb[(size_t)i3 * 32 + lane32];
        s0 += bl(p0); s1 += bh(p0);
        t0 += bl(p1); t1 += bh(p1);
        u0 += bl(p2); u1 += bh(p2);
        v0 += bl(p3); v1 += bh(p3);
    }
    for (; k < n1; ++k) {
        int i0 = __shfl(idxA, k, 32);
        unsigned p0 = ylb[(size_t)i0 * 32 + lane32];
        s0 += bl(p0); s1 += bh(p0);
    }
    const int n2 = n - 32;
    k = 0;
    for (; k + 4 <= n2; k += 4) {
        int i0 = __shfl(idxB, k, 32), i1 = __shfl(idxB, k + 1, 32);
        int i2 = __shfl(idxB, k + 2, 32), i3 = __shfl(idxB, k + 3, 32);
        unsigned p0 = ylb[(size_t)i0 * 32 + lane32];
        unsigned p1 = ylb[(size_t)i1 * 32 + lane32];
        unsigned p2 = ylb[(size_t)i2 * 32 + lane32];
        unsigned p3 = ylb[(size_t)i3 * 32 + lane32];
        s0 += bl(p0); s1 += bh(p0);
        t0 += bl(p1); t1 += bh(p1);
        u0 += bl(p2); u1 += bh(p2);
        v0 += bl(p3); v1 += bh(p3);
    }
    for (; k < n2; ++k) {
        int i0 = __shfl(idxB, k, 32);
        unsigned p0 = ylb[(size_t)i0 * 32 + lane32];
        s0 += bl(p0); s1 += bh(p0);
    }

    const float inv = 1.f / fmaxf((float)deg, 1.f);
    const float m0 = ((s0 + t0) + (u0 + v0)) * inv;
    const float m1 = ((s1 + t1) + (u1 + v1)) * inv;

    float2* po = (float2*)&out[(size_t)node * D + lane32 * 2];
    float2 rr = *po;
    rr.x = fmaxf(m0 + rr.x, 0.f);
    rr.y = fmaxf(m1 + rr.y, 0.f);
    *po = rr;
}

extern "C" void kernel_launch(void* const* d_in, const int* in_sizes, int n_in,
                              void* d_out, int out_size, void* d_ws, size_t ws_size,
                              hipStream_t stream) {
    const float* x  = (const float*)d_in[0];
    const int*   ei = (const int*)d_in[1];      // [2, E]: row 0 = src, row 1 = dst
    const float* Wl = (const float*)d_in[2];
    const float* Wr = (const float*)d_in[3];
    const float* b  = (const float*)d_in[4];
    float*       out = (float*)d_out;

    const int nN = in_sizes[0] / D;   // 100000
    const int nE = in_sizes[1] / 2;   // 1600000
    const int* src = ei;
    const int* dst = ei + nE;

    const int nB = (nN + 127) >> NBKT_SHIFT;     // 782 buckets

    // ws layout: cursor[nB*PAD] | pairs[nB*capB] | cnt[nN] | ylb[nN*64 bf16]
    // Defensive signed sizing (R1 lesson). capN = slots per node, capB = 128*capN
    // so the bucket layout is node-linear. capN=45: P(Poisson(16) > 45) ~ 1e-10.
    long long ws_words = (long long)(ws_size / 4);
    long long avail = ws_words - (long long)nB * PAD - (long long)nN
                    - (long long)nN * (D / 2) - 64;
    if (avail < 0) avail = 0;
    long long capBL = avail / (long long)nB;
    int capN = (int)(capBL / 128);
    if (capN > 45) capN = 45;
    if (capN < 4)  capN = 4;
    const int capB = capN * 128;

    int* cursor = (int*)d_ws;
    int* pairs  = cursor + (size_t)nB * PAD;
    int* cnt    = pairs + (size_t)nB * capB;
    size_t off = (size_t)nB * PAD + (size_t)nB * capB + (size_t)nN;
    off = (off + 3) & ~(size_t)3;                // 16B-align ylb
    unsigned short* ylb = (unsigned short*)((int*)d_ws + off);

    hipMemsetAsync(cursor, 0, (size_t)nB * PAD * sizeof(int), stream);

    const int nA    = (nE + CHUNK - 1) / CHUNK;  // 196 scatter chunks
    const int nPre  = (nN + 63) / 64;            // 1563 pre-GEMM tiles
    const int total = nA + nPre;                 // 1759, interleaved

    k_combo<<<total, 256, 0, stream>>>(x, src, dst, Wl, Wr, b,
                                       cursor, pairs, ylb, out,
                                       nE, nN, nB, capB, nA, total);
    k_sort<<<nB, 256, 0, stream>>>(pairs, cursor, cnt, nN, nB, capB, capN);
    k_gather<<<(nN + 7) / 8, 256, 0, stream>>>((const unsigned int*)ylb, cnt,
                                               pairs, out, nN, capN);
}

// Round 4
// 195.492 us; speedup vs baseline: 6.0192x; 1.0274x over previous
//
#include <hip/hip_runtime.h>
#include <hip/hip_bf16.h>

#define D 64
#define CHUNK 4096        // edges per scatter chunk-block
#define NBKT_SHIFT 7      // 128 nodes per bucket
#define PAD 16            // cursor padding: one counter per 64B line (R2 lesson)

// ---------------- K1: chunked edge scatter (standalone) ----------------
// Per 4096-edge chunk: (a) LDS int histogram over 782 buckets (dst staged in
// LDS, read once), (b) ONE global atomicAdd per (chunk,bucket) ~ 306K total,
// cursors one-per-64B-line so serialization is 391 ops/line ~ 5us,
// (c) LDS-rank + write packed (dloc<<17|src) into the bucket's reserved run.
__global__ __launch_bounds__(256) void k_scatter(
        const int* __restrict__ src, const int* __restrict__ dst,
        int* __restrict__ cursor, int* __restrict__ pairs,
        int nE, int nB, int capB) {
    __shared__ int hA[800], bL[800], hC[800];   // 9.6KB (782 used)
    __shared__ int sDst[CHUNK];                 // 16KB
    const int t = threadIdx.x;
    const int e0 = blockIdx.x * CHUNK;
    const int cnt = min(CHUNK, nE - e0);

    for (int i = t; i < nB; i += 256) { hA[i] = 0; hC[i] = 0; }
    __syncthreads();
    for (int i = t; i < cnt; i += 256) {
        int d = dst[e0 + i];
        sDst[i] = d;
        atomicAdd(&hA[d >> NBKT_SHIFT], 1);     // native LDS int atomic
    }
    __syncthreads();
    for (int i = t; i < nB; i += 256) {
        int c = hA[i];
        bL[i] = (c > 0) ? atomicAdd(&cursor[i * PAD], c) : 0;
    }
    __syncthreads();
    for (int i = t; i < cnt; i += 256) {
        int d = sDst[i];
        int sn = src[e0 + i];
        int bk = d >> NBKT_SHIFT;
        int r = atomicAdd(&hC[bk], 1);
        int p = bL[bk] + r;
        if (p < capB)                            // >40-sigma guard
            pairs[(size_t)bk * capB + p] = ((d & 127) << 17) | sn;
    }
}

// ---------------- K2: pre-GEMM, weights + x^T in LDS ----------------
// R3 lesson: per-thread weight re-reads from global = ~818MB of L1/L2 traffic
// (invisible in FETCH_SIZE). Stage Wl,Wr (32KB) in LDS: reads become 64B-unique
// 16-way-broadcast (free). x staged TRANSPOSED (stride 65: (col+row)%32 bank
// map -> 2-way alias, free) so the 4-row A fragment is one ds_read_b128.
// ylb = x@W_l (bf16), out = x@W_r + b (f32, no relu yet).
__global__ __launch_bounds__(256) void k_pre(
        const float* __restrict__ x, const float* __restrict__ Wl,
        const float* __restrict__ Wr, const float* __restrict__ b,
        unsigned short* __restrict__ ylb, float* __restrict__ out, int nN) {
    __shared__ float sXT[64 * 65];      // sXT[k*65+n] = x[tile+n][k]; 16.6KB
    __shared__ float4 sW4[2048];        // [0,1024)=Wl, [1024,2048)=Wr; 32KB
    __shared__ float sB[64];

    const int t = threadIdx.x;
    const int tile = blockIdx.x * 64;

    {
        const float4* wl4p = (const float4*)Wl;
        const float4* wr4p = (const float4*)Wr;
#pragma unroll
        for (int i = 0; i < 4; ++i) {
            int idx = t + i * 256;                 // 0..1023
            sW4[idx] = wl4p[idx];
            sW4[1024 + idx] = wr4p[idx];
        }
    }
    if (t < 64) sB[t] = b[t];
#pragma unroll
    for (int i = 0; i < 4; ++i) {
        int idx = t + i * 256;          // 0..1023
        int row = idx >> 4;             // 0..63
        int col4 = (idx & 15) * 4;      // 0..60
        int gg = tile + row;
        float4 v = (gg < nN) ? *(const float4*)&x[(size_t)gg * D + col4]
                             : make_float4(0.f, 0.f, 0.f, 0.f);
        sXT[(col4 + 0) * 65 + row] = v.x;
        sXT[(col4 + 1) * 65 + row] = v.y;
        sXT[(col4 + 2) * 65 + row] = v.z;
        sXT[(col4 + 3) * 65 + row] = v.w;
    }
    __syncthreads();

    const int n0 = (t & 15) * 4;        // output rows n0..n0+3
    const int c0v = t >> 4;             // output cols c0v*4..+3
    float accl[4][4] = {}, accr[4][4] = {};
#pragma unroll 4
    for (int k = 0; k < D; ++k) {
        float4 a4  = *(const float4*)&sXT[k * 65 + n0];   // rows n0..n0+3 @ k
        float4 wl4 = sW4[k * 16 + c0v];                   // broadcast, free
        float4 wr4 = sW4[1024 + k * 16 + c0v];
        accl[0][0] += a4.x * wl4.x; accl[0][1] += a4.x * wl4.y; accl[0][2] += a4.x * wl4.z; accl[0][3] += a4.x * wl4.w;
        accl[1][0] += a4.y * wl4.x; accl[1][1] += a4.y * wl4.y; accl[1][2] += a4.y * wl4.z; accl[1][3] += a4.y * wl4.w;
        accl[2][0] += a4.z * wl4.x; accl[2][1] += a4.z * wl4.y; accl[2][2] += a4.z * wl4.z; accl[2][3] += a4.z * wl4.w;
        accl[3][0] += a4.w * wl4.x; accl[3][1] += a4.w * wl4.y; accl[3][2] += a4.w * wl4.z; accl[3][3] += a4.w * wl4.w;
        accr[0][0] += a4.x * wr4.x; accr[0][1] += a4.x * wr4.y; accr[0][2] += a4.x * wr4.z; accr[0][3] += a4.x * wr4.w;
        accr[1][0] += a4.y * wr4.x; accr[1][1] += a4.y * wr4.y; accr[1][2] += a4.y * wr4.z; accr[1][3] += a4.y * wr4.w;
        accr[2][0] += a4.z * wr4.x; accr[2][1] += a4.z * wr4.y; accr[2][2] += a4.z * wr4.z; accr[2][3] += a4.z * wr4.w;
        accr[3][0] += a4.w * wr4.x; accr[3][1] += a4.w * wr4.y; accr[3][2] += a4.w * wr4.z; accr[3][3] += a4.w * wr4.w;
    }

    const int c0 = c0v * 4;
#pragma unroll
    for (int i = 0; i < 4; ++i) {
        int gg = tile + n0 + i;
        if (gg >= nN) continue;
        __hip_bfloat162 l01 = __float22bfloat162_rn(make_float2(accl[i][0], accl[i][1]));
        __hip_bfloat162 l23 = __float22bfloat162_rn(make_float2(accl[i][2], accl[i][3]));
        uint2 pl = make_uint2(*(unsigned int*)&l01, *(unsigned int*)&l23);
        *(uint2*)&ylb[(size_t)gg * D + c0] = pl;
        float4 o;
        o.x = accr[i][0] + sB[c0 + 0];
        o.y = accr[i][1] + sB[c0 + 1];
        o.z = accr[i][2] + sB[c0 + 2];
        o.w = accr[i][3] + sB[c0 + 3];
        *(float4*)&out[(size_t)gg * D + c0] = o;   // self term, f32, no relu yet
    }
}

// ---------------- K3: bucket-grouped -> per-node slot layout (in-place) ------
// Register-staged (static indexing, rule #20), barrier (loads drained), then
// LDS-rank and scatter to node-linear slots. Writes exact degree to cnt.
__global__ __launch_bounds__(256) void k_sort(
        int* __restrict__ pairs, const int* __restrict__ cursor,
        int* __restrict__ cnt, int nN, int nB, int capB, int capN) {
    __shared__ int h[128];
    const int bkt = blockIdx.x;
    const int t = threadIdx.x;
    const size_t base = (size_t)bkt * capB;

    if (t < 128) h[t] = 0;
    const int n = min(cursor[bkt * PAD], capB);

    int st[23];   // 23*256 = 5888 >= capB max 5760
#pragma unroll
    for (int j = 0; j < 23; ++j) {
        int i = t + j * 256;
        st[j] = (i < n) ? pairs[base + i] : -1;
    }
    __syncthreads();   // loads drained + h zeroed

#pragma unroll
    for (int j = 0; j < 23; ++j) {
        int v = st[j];
        if (v >= 0 && v < (1 << 24)) {
            int dl = v >> 17;
            int r = atomicAdd(&h[dl], 1);
            if (r < capN) pairs[base + dl * capN + r] = v & 0x1FFFF;
        }
    }
    __syncthreads();

    if (t < 128) {
        int nd = bkt * 128 + t;
        if (nd < nN) cnt[nd] = h[t];
    }
}

// ---------------- K4: gather-mean + finalize (proven, verbatim) -----------
__device__ __forceinline__ float bl(unsigned p) { return __uint_as_float(p << 16); }
__device__ __forceinline__ float bh(unsigned p) { return __uint_as_float(p & 0xffff0000u); }

__global__ __launch_bounds__(256) void k_gather(
        const unsigned int* __restrict__ ylb, const int* __restrict__ cnt,
        const int* __restrict__ slots, float* __restrict__ out, int nN, int cap) {
    const int t = threadIdx.x;
    const int lane32 = t & 31;
    const int node = blockIdx.x * 8 + (t >> 5);
    if (node >= nN) return;

    const int deg = cnt[node];
    const int n = min(deg, cap);
    const size_t base = (size_t)node * cap;

    int idxA = (lane32 < n) ? slots[base + lane32] : 0;
    int idxB = (32 + lane32 < n) ? slots[base + 32 + lane32] : 0;

    float s0 = 0.f, s1 = 0.f, t0 = 0.f, t1 = 0.f;
    float u0 = 0.f, u1 = 0.f, v0 = 0.f, v1 = 0.f;

    const int n1 = min(n, 32);
    int k = 0;
    for (; k + 4 <= n1; k += 4) {
        int i0 = __shfl(idxA, k, 32), i1 = __shfl(idxA, k + 1, 32);
        int i2 = __shfl(idxA, k + 2, 32), i3 = __shfl(idxA, k + 3, 32);
        unsigned p0 = ylb[(size_t)i0 * 32 + lane32];
        unsigned p1 = ylb[(size_t)i1 * 32 + lane32];
        unsigned p2 = ylb[(size_t)i2 * 32 + lane32];
        unsigned p3 = ylb[(size_t)i3 * 32 + lane32];
        s0 += bl(p0); s1 += bh(p0);
        t0 += bl(p1); t1 += bh(p1);
        u0 += bl(p2); u1 += bh(p2);
        v0 += bl(p3); v1 += bh(p3);
    }
    for (; k < n1; ++k) {
        int i0 = __shfl(idxA, k, 32);
        unsigned p0 = ylb[(size_t)i0 * 32 + lane32];
        s0 += bl(p0); s1 += bh(p0);
    }
    const int n2 = n - 32;
    k = 0;
    for (; k + 4 <= n2; k += 4) {
        int i0 = __shfl(idxB, k, 32), i1 = __shfl(idxB, k + 1, 32);
        int i2 = __shfl(idxB, k + 2, 32), i3 = __shfl(idxB, k + 3, 32);
        unsigned p0 = ylb[(size_t)i0 * 32 + lane32];
        unsigned p1 = ylb[(size_t)i1 * 32 + lane32];
        unsigned p2 = ylb[(size_t)i2 * 32 + lane32];
        unsigned p3 = ylb[(size_t)i3 * 32 + lane32];
        s0 += bl(p0); s1 += bh(p0);
        t0 += bl(p1); t1 += bh(p1);
        u0 += bl(p2); u1 += bh(p2);
        v0 += bl(p3); v1 += bh(p3);
    }
    for (; k < n2; ++k) {
        int i0 = __shfl(idxB, k, 32);
        unsigned p0 = ylb[(size_t)i0 * 32 + lane32];
        s0 += bl(p0); s1 += bh(p0);
    }

    const float inv = 1.f / fmaxf((float)deg, 1.f);
    const float m0 = ((s0 + t0) + (u0 + v0)) * inv;
    const float m1 = ((s1 + t1) + (u1 + v1)) * inv;

    float2* po = (float2*)&out[(size_t)node * D + lane32 * 2];
    float2 rr = *po;
    rr.x = fmaxf(m0 + rr.x, 0.f);
    rr.y = fmaxf(m1 + rr.y, 0.f);
    *po = rr;
}

extern "C" void kernel_launch(void* const* d_in, const int* in_sizes, int n_in,
                              void* d_out, int out_size, void* d_ws, size_t ws_size,
                              hipStream_t stream) {
    const float* x  = (const float*)d_in[0];
    const int*   ei = (const int*)d_in[1];      // [2, E]: row 0 = src, row 1 = dst
    const float* Wl = (const float*)d_in[2];
    const float* Wr = (const float*)d_in[3];
    const float* b  = (const float*)d_in[4];
    float*       out = (float*)d_out;

    const int nN = in_sizes[0] / D;   // 100000
    const int nE = in_sizes[1] / 2;   // 1600000
    const int* src = ei;
    const int* dst = ei + nE;

    const int nB = (nN + 127) >> NBKT_SHIFT;     // 782 buckets

    // ws layout: cursor[nB*PAD] | pairs[nB*capB] | cnt[nN] | ylb[nN*64 bf16]
    // Defensive signed sizing (R1 lesson). capB = 128*capN -> node-linear.
    long long ws_words = (long long)(ws_size / 4);
    long long avail = ws_words - (long long)nB * PAD - (long long)nN
                    - (long long)nN * (D / 2) - 64;
    if (avail < 0) avail = 0;
    long long capBL = avail / (long long)nB;
    int capN = (int)(capBL / 128);
    if (capN > 45) capN = 45;
    if (capN < 4)  capN = 4;
    const int capB = capN * 128;

    int* cursor = (int*)d_ws;
    int* pairs  = cursor + (size_t)nB * PAD;
    int* cnt    = pairs + (size_t)nB * capB;
    size_t off = (size_t)nB * PAD + (size_t)nB * capB + (size_t)nN;
    off = (off + 3) & ~(size_t)3;                // 16B-align ylb
    unsigned short* ylb = (unsigned short*)((int*)d_ws + off);

    hipMemsetAsync(cursor, 0, (size_t)nB * PAD * sizeof(int), stream);

    k_scatter<<<(nE + CHUNK - 1) / CHUNK, 256, 0, stream>>>(src, dst, cursor, pairs, nE, nB, capB);
    k_pre<<<(nN + 63) / 64, 256, 0, stream>>>(x, Wl, Wr, b, ylb, out, nN);
    k_sort<<<nB, 256, 0, stream>>>(pairs, cursor, cnt, nN, nB, capB, capN);
    k_gather<<<(nN + 7) / 8, 256, 0, stream>>>((const unsigned int*)ylb, cnt,
                                               pairs, out, nN, capN);
}

// Round 5
// 182.893 us; speedup vs baseline: 6.4339x; 1.0689x over previous
//
#include <hip/hip_runtime.h>
#include <hip/hip_bf16.h>

#define D 64
#define CHUNK 4096        // edges per scatter chunk-block
#define NBKT_SHIFT 7      // 128 nodes per bucket
#define NSUB 8            // sub-cursors per bucket (XCD-spread, R4 lesson)
#define SUBCAP 720        // entries per sub-run: mean 256, +29 sigma
#define CAPN 45           // slots per node: P(Poisson(16) > 45) ~ 1e-10
#define CAPB (CAPN * 128) // 5760 = NSUB * SUBCAP
#define PAD 16            // cursor padding: one counter per 64B line (R2 lesson)

// ---------------- K1: chunked edge scatter ----------------
// R4 post-mortem: 47us was the cursor-reservation bounce — 391 sparse
// atomic-RMWs per line at ~300cy cross-L2 each. Fixes: (1) 8-way sub-cursors
// (49 ops/line, XCD-local via bid&7), (2) src+dst register-staged once
// (no re-read, no LDS round-trip), (3) rotated reservation scan (no convoy).
__global__ __launch_bounds__(256) void k_scatter(
        const int* __restrict__ src, const int* __restrict__ dst,
        int* __restrict__ cursor, int* __restrict__ pairs,
        int nE, int nB) {
    __shared__ int hA[800], bL[800], hC[800];   // 9.6KB (782 used)
    const int t = threadIdx.x;
    const int bid = blockIdx.x;
    const int e0 = bid * CHUNK;
    const int cnt = min(CHUNK, nE - e0);
    const int sub = bid & (NSUB - 1);

    // stage the chunk in registers: all 32 loads issued up-front
    int rd[16], rs[16];
#pragma unroll
    for (int j = 0; j < 16; ++j) {
        int i = t + j * 256;
        rd[j] = (i < cnt) ? dst[e0 + i] : -1;
    }
#pragma unroll
    for (int j = 0; j < 16; ++j) {
        int i = t + j * 256;
        rs[j] = (i < cnt) ? src[e0 + i] : 0;
    }

    for (int i = t; i < nB; i += 256) { hA[i] = 0; hC[i] = 0; }
    __syncthreads();
    // (a) histogram (native LDS int atomics, ~5 ops/counter)
#pragma unroll
    for (int j = 0; j < 16; ++j)
        if (rd[j] >= 0) atomicAdd(&hA[rd[j] >> NBKT_SHIFT], 1);
    __syncthreads();
    // (b) reserve runs; rotated start so blocks don't convoy on cursor lines
    const int start = (bid * 401) % nB;        // 401 coprime with 782
    for (int i = t; i < nB; i += 256) {
        int bk = i + start; if (bk >= nB) bk -= nB;
        int c = hA[bk];
        bL[bk] = (c > 0) ? atomicAdd(&cursor[(bk * NSUB + sub) * PAD], c) : 0;
    }
    __syncthreads();
    // (c) rank + write into this chunk's sub-run
#pragma unroll
    for (int j = 0; j < 16; ++j) {
        int d = rd[j];
        if (d < 0) continue;
        int bk = d >> NBKT_SHIFT;
        int r = atomicAdd(&hC[bk], 1);
        int p = bL[bk] + r;
        if (p < SUBCAP)                         // >29-sigma guard
            pairs[(size_t)bk * CAPB + sub * SUBCAP + p] = ((d & 127) << 17) | rs[j];
    }
}

// ---------------- K2: pre-GEMM, weights + x^T in LDS (R4-proven) ----------
__global__ __launch_bounds__(256) void k_pre(
        const float* __restrict__ x, const float* __restrict__ Wl,
        const float* __restrict__ Wr, const float* __restrict__ b,
        unsigned short* __restrict__ ylb, float* __restrict__ out, int nN) {
    __shared__ float sXT[64 * 65];      // sXT[k*65+n] = x[tile+n][k]; 16.6KB
    __shared__ float4 sW4[2048];        // [0,1024)=Wl, [1024,2048)=Wr; 32KB
    __shared__ float sB[64];

    const int t = threadIdx.x;
    const int tile = blockIdx.x * 64;

    {
        const float4* wl4p = (const float4*)Wl;
        const float4* wr4p = (const float4*)Wr;
#pragma unroll
        for (int i = 0; i < 4; ++i) {
            int idx = t + i * 256;                 // 0..1023
            sW4[idx] = wl4p[idx];
            sW4[1024 + idx] = wr4p[idx];
        }
    }
    if (t < 64) sB[t] = b[t];
#pragma unroll
    for (int i = 0; i < 4; ++i) {
        int idx = t + i * 256;          // 0..1023
        int row = idx >> 4;             // 0..63
        int col4 = (idx & 15) * 4;      // 0..60
        int gg = tile + row;
        float4 v = (gg < nN) ? *(const float4*)&x[(size_t)gg * D + col4]
                             : make_float4(0.f, 0.f, 0.f, 0.f);
        sXT[(col4 + 0) * 65 + row] = v.x;
        sXT[(col4 + 1) * 65 + row] = v.y;
        sXT[(col4 + 2) * 65 + row] = v.z;
        sXT[(col4 + 3) * 65 + row] = v.w;
    }
    __syncthreads();

    const int n0 = (t & 15) * 4;        // output rows n0..n0+3
    const int c0v = t >> 4;             // output cols c0v*4..+3
    float accl[4][4] = {}, accr[4][4] = {};
#pragma unroll 4
    for (int k = 0; k < D; ++k) {
        float4 a4  = *(const float4*)&sXT[k * 65 + n0];   // rows n0..n0+3 @ k
        float4 wl4 = sW4[k * 16 + c0v];                   // broadcast, free
        float4 wr4 = sW4[1024 + k * 16 + c0v];
        accl[0][0] += a4.x * wl4.x; accl[0][1] += a4.x * wl4.y; accl[0][2] += a4.x * wl4.z; accl[0][3] += a4.x * wl4.w;
        accl[1][0] += a4.y * wl4.x; accl[1][1] += a4.y * wl4.y; accl[1][2] += a4.y * wl4.z; accl[1][3] += a4.y * wl4.w;
        accl[2][0] += a4.z * wl4.x; accl[2][1] += a4.z * wl4.y; accl[2][2] += a4.z * wl4.z; accl[2][3] += a4.z * wl4.w;
        accl[3][0] += a4.w * wl4.x; accl[3][1] += a4.w * wl4.y; accl[3][2] += a4.w * wl4.z; accl[3][3] += a4.w * wl4.w;
        accr[0][0] += a4.x * wr4.x; accr[0][1] += a4.x * wr4.y; accr[0][2] += a4.x * wr4.z; accr[0][3] += a4.x * wr4.w;
        accr[1][0] += a4.y * wr4.x; accr[1][1] += a4.y * wr4.y; accr[1][2] += a4.y * wr4.z; accr[1][3] += a4.y * wr4.w;
        accr[2][0] += a4.z * wr4.x; accr[2][1] += a4.z * wr4.y; accr[2][2] += a4.z * wr4.z; accr[2][3] += a4.z * wr4.w;
        accr[3][0] += a4.w * wr4.x; accr[3][1] += a4.w * wr4.y; accr[3][2] += a4.w * wr4.z; accr[3][3] += a4.w * wr4.w;
    }

    const int c0 = c0v * 4;
#pragma unroll
    for (int i = 0; i < 4; ++i) {
        int gg = tile + n0 + i;
        if (gg >= nN) continue;
        __hip_bfloat162 l01 = __float22bfloat162_rn(make_float2(accl[i][0], accl[i][1]));
        __hip_bfloat162 l23 = __float22bfloat162_rn(make_float2(accl[i][2], accl[i][3]));
        uint2 pl = make_uint2(*(unsigned int*)&l01, *(unsigned int*)&l23);
        *(uint2*)&ylb[(size_t)gg * D + c0] = pl;
        float4 o;
        o.x = accr[i][0] + sB[c0 + 0];
        o.y = accr[i][1] + sB[c0 + 1];
        o.z = accr[i][2] + sB[c0 + 2];
        o.w = accr[i][3] + sB[c0 + 3];
        *(float4*)&out[(size_t)gg * D + c0] = o;   // self term, f32, no relu yet
    }
}

// ---------------- K3: bucket-grouped (8 sub-runs) -> node-linear slots ------
// Register-staged (static indexing, rule #20), barrier (loads drained before
// any in-place store), LDS-rank, scatter to node*CAPN. Exact degree to cnt.
__global__ __launch_bounds__(256) void k_sort(
        int* __restrict__ pairs, const int* __restrict__ cursor,
        int* __restrict__ cnt, int nN, int nB) {
    __shared__ int h[128];
    const int bkt = blockIdx.x;
    const int t = threadIdx.x;
    const size_t base = (size_t)bkt * CAPB;

    if (t < 128) h[t] = 0;

    int st[24];   // 8 sub-runs x 3 reads (SUBCAP=720 <= 3*256)
#pragma unroll
    for (int j = 0; j < NSUB; ++j) {
        int c = min(cursor[(bkt * NSUB + j) * PAD], SUBCAP);
#pragma unroll
        for (int w = 0; w < 3; ++w) {
            int i = t + w * 256;
            st[j * 3 + w] = (i < c) ? pairs[base + j * SUBCAP + i] : -1;
        }
    }
    __syncthreads();   // all staging loads drained + h zeroed

#pragma unroll
    for (int j = 0; j < 24; ++j) {
        int v = st[j];
        if (v >= 0) {
            int dl = v >> 17;
            int r = atomicAdd(&h[dl], 1);
            if (r < CAPN) pairs[base + dl * CAPN + r] = v & 0x1FFFF;
        }
    }
    __syncthreads();

    if (t < 128) {
        int nd = bkt * 128 + t;
        if (nd < nN) cnt[nd] = h[t];
    }
}

// ---------------- K4: gather-mean + finalize (proven, verbatim) -----------
__device__ __forceinline__ float bl(unsigned p) { return __uint_as_float(p << 16); }
__device__ __forceinline__ float bh(unsigned p) { return __uint_as_float(p & 0xffff0000u); }

__global__ __launch_bounds__(256) void k_gather(
        const unsigned int* __restrict__ ylb, const int* __restrict__ cnt,
        const int* __restrict__ slots, float* __restrict__ out, int nN, int cap) {
    const int t = threadIdx.x;
    const int lane32 = t & 31;
    const int node = blockIdx.x * 8 + (t >> 5);
    if (node >= nN) return;

    const int deg = cnt[node];
    const int n = min(deg, cap);
    const size_t base = (size_t)node * cap;

    int idxA = (lane32 < n) ? slots[base + lane32] : 0;
    int idxB = (32 + lane32 < n) ? slots[base + 32 + lane32] : 0;

    float s0 = 0.f, s1 = 0.f, t0 = 0.f, t1 = 0.f;
    float u0 = 0.f, u1 = 0.f, v0 = 0.f, v1 = 0.f;

    const int n1 = min(n, 32);
    int k = 0;
    for (; k + 4 <= n1; k += 4) {
        int i0 = __shfl(idxA, k, 32), i1 = __shfl(idxA, k + 1, 32);
        int i2 = __shfl(idxA, k + 2, 32), i3 = __shfl(idxA, k + 3, 32);
        unsigned p0 = ylb[(size_t)i0 * 32 + lane32];
        unsigned p1 = ylb[(size_t)i1 * 32 + lane32];
        unsigned p2 = ylb[(size_t)i2 * 32 + lane32];
        unsigned p3 = ylb[(size_t)i3 * 32 + lane32];
        s0 += bl(p0); s1 += bh(p0);
        t0 += bl(p1); t1 += bh(p1);
        u0 += bl(p2); u1 += bh(p2);
        v0 += bl(p3); v1 += bh(p3);
    }
    for (; k < n1; ++k) {
        int i0 = __shfl(idxA, k, 32);
        unsigned p0 = ylb[(size_t)i0 * 32 + lane32];
        s0 += bl(p0); s1 += bh(p0);
    }
    const int n2 = n - 32;
    k = 0;
    for (; k + 4 <= n2; k += 4) {
        int i0 = __shfl(idxB, k, 32), i1 = __shfl(idxB, k + 1, 32);
        int i2 = __shfl(idxB, k + 2, 32), i3 = __shfl(idxB, k + 3, 32);
        unsigned p0 = ylb[(size_t)i0 * 32 + lane32];
        unsigned p1 = ylb[(size_t)i1 * 32 + lane32];
        unsigned p2 = ylb[(size_t)i2 * 32 + lane32];
        unsigned p3 = ylb[(size_t)i3 * 32 + lane32];
        s0 += bl(p0); s1 += bh(p0);
        t0 += bl(p1); t1 += bh(p1);
        u0 += bl(p2); u1 += bh(p2);
        v0 += bl(p3); v1 += bh(p3);
    }
    for (; k < n2; ++k) {
        int i0 = __shfl(idxB, k, 32);
        unsigned p0 = ylb[(size_t)i0 * 32 + lane32];
        s0 += bl(p0); s1 += bh(p0);
    }

    const float inv = 1.f / fmaxf((float)deg, 1.f);
    const float m0 = ((s0 + t0) + (u0 + v0)) * inv;
    const float m1 = ((s1 + t1) + (u1 + v1)) * inv;

    float2* po = (float2*)&out[(size_t)node * D + lane32 * 2];
    float2 rr = *po;
    rr.x = fmaxf(m0 + rr.x, 0.f);
    rr.y = fmaxf(m1 + rr.y, 0.f);
    *po = rr;
}

extern "C" void kernel_launch(void* const* d_in, const int* in_sizes, int n_in,
                              void* d_out, int out_size, void* d_ws, size_t ws_size,
                              hipStream_t stream) {
    const float* x  = (const float*)d_in[0];
    const int*   ei = (const int*)d_in[1];      // [2, E]: row 0 = src, row 1 = dst
    const float* Wl = (const float*)d_in[2];
    const float* Wr = (const float*)d_in[3];
    const float* b  = (const float*)d_in[4];
    float*       out = (float*)d_out;

    const int nN = in_sizes[0] / D;   // 100000
    const int nE = in_sizes[1] / 2;   // 1600000
    const int* src = ei;
    const int* dst = ei + nE;

    const int nB = (nN + 127) >> NBKT_SHIFT;     // 782 buckets

    // ws layout: cursor[nB*NSUB*PAD] | pairs[nB*CAPB] | cnt[nN] | ylb[nN*64 bf16]
    // = 0.4 + 18.0 + 0.4 + 12.8 MB = 31.6 MB (R4 ran with 31.25 -> fits ~33MB ws)
    int* cursor = (int*)d_ws;
    int* pairs  = cursor + (size_t)nB * NSUB * PAD;
    int* cnt    = pairs + (size_t)nB * CAPB;
    size_t off = (size_t)nB * NSUB * PAD + (size_t)nB * CAPB + (size_t)nN;
    off = (off + 3) & ~(size_t)3;                // 16B-align ylb
    unsigned short* ylb = (unsigned short*)((int*)d_ws + off);

    hipMemsetAsync(cursor, 0, (size_t)nB * NSUB * PAD * sizeof(int), stream);

    k_scatter<<<(nE + CHUNK - 1) / CHUNK, 256, 0, stream>>>(src, dst, cursor, pairs, nE, nB);
    k_pre<<<(nN + 63) / 64, 256, 0, stream>>>(x, Wl, Wr, b, ylb, out, nN);
    k_sort<<<nB, 256, 0, stream>>>(pairs, cursor, cnt, nN, nB);
    k_gather<<<(nN + 7) / 8, 256, 0, stream>>>((const unsigned int*)ylb, cnt,
                                               pairs, out, nN, CAPN);
}